// Round 11
// baseline (277.440 us; speedup 1.0000x reference)
//
#include <hip/hip_runtime.h>

// SwitchGNN split pipeline (R10 + nt-store aggb + 2-phase pipelined GEMM):
//  out = (1/7) * sum_t [ (segsum_t(x[src]) / max(cnt,1)) @ W_t + 1{cnt>0} b_t ]
// P0 convx_k: x -> bf16 rows (256B each)
// P1 wconv_k: W -> bf16, transposed [t][f][k], XOR-swizzled
// P2 fill_k : bucket edges by (dst,type), XCD-partitioned, nt edge reads
// P3 agg_k  : one wave per node, 4 gather chains; aggb stores NONTEMPORAL so
//             the 175MB write stream stops evicting xb from L3 (R10: FETCH
//             209MB for a 25.6MB table = xb thrash)
// P4 gemm_k : BK=64 double-buffered pipeline: stage(s+1) issued BEFORE
//             MFMA(s), counted "s_waitcnt vmcnt(4)"+s_barrier (never drains
//             the prefetch), 2 barriers/step. 64KB LDS -> 2 blocks/CU.

constexpr int NN = 100000;
constexpr int NT = 7;
constexpr int NE = 250000;
constexpr int DD = 128;
constexpr int CAP = 20;           // max tracked edges per (n,t); P(Poisson(2.5)>20)~3e-12
constexpr int OVF = CAP - 8;      // overflow slots beyond the 8 fast slots
constexpr int NROWS = ((NN + 127) / 128) * 128;   // 100096 padded rows
constexpr int NPART = 8;                          // dst partitions = XCDs
constexpr int PSIZE = (NN + NPART - 1) / NPART;   // 12500 nodes per partition
constexpr int EPB = 1024;                         // edges per fill block
constexpr int NSLAB = (NE + EPB - 1) / EPB;       // 245 slabs

typedef short bf16x8 __attribute__((ext_vector_type(8)));
typedef float f32x4 __attribute__((ext_vector_type(4)));
typedef float f32x2 __attribute__((ext_vector_type(2)));
typedef int   i32x4 __attribute__((ext_vector_type(4)));
typedef float fltx4 __attribute__((ext_vector_type(4)));

__device__ __forceinline__ unsigned pack_bf16x2(float lo, float hi) {
    unsigned a = __float_as_uint(lo), b = __float_as_uint(hi);
    unsigned al = (a + 0x7FFFu + ((a >> 16) & 1u)) >> 16;          // RNE
    unsigned bh = (b + 0x7FFFu + ((b >> 16) & 1u)) & 0xFFFF0000u;
    return al | bh;
}

// ---------------------------------------------------------------- conv x ----
__global__ __launch_bounds__(256) void convx_k(
    const float* __restrict__ x, uint4* __restrict__ xb)
{
    int id = blockIdx.x * 256 + threadIdx.x;
    const fltx4* src = (const fltx4*)x;
    fltx4 v0 = __builtin_nontemporal_load(src + (size_t)id * 2);
    fltx4 v1 = __builtin_nontemporal_load(src + (size_t)id * 2 + 1);
    uint4 o;
    o.x = pack_bf16x2(v0[0], v0[1]);
    o.y = pack_bf16x2(v0[2], v0[3]);
    o.z = pack_bf16x2(v1[0], v1[1]);
    o.w = pack_bf16x2(v1[2], v1[3]);
    xb[id] = o;
}

// ---------------------------------------------------------------- W conv ----
// WTb[t][f][k] bf16, row=256B, granule ^= f&7. One wave per (t,f).
__global__ __launch_bounds__(256) void wconv_k(
    const float* __restrict__ W, char* __restrict__ WTb)
{
    int wid = (blockIdx.x * 256 + threadIdx.x) >> 6;
    int lane = threadIdx.x & 63;
    int t = wid >> 7, f = wid & 127;
    if (t >= NT) return;
    const float* Wt = W + (size_t)t * DD * DD;
    float w0 = Wt[(size_t)(2 * lane) * DD + f];
    float w1 = Wt[(size_t)(2 * lane + 1) * DD + f];
    int gran = (lane >> 2) ^ (f & 7);
    *(unsigned*)(WTb + (size_t)t * 32768 + f * 256 + gran * 16 + (lane & 3) * 4)
        = pack_bf16x2(w0, w1);
}

// ------------------------------------------------------------------ fill ----
__global__ __launch_bounds__(256) void fill_k(
    const int* __restrict__ ei,      // [NT][2][NE]
    int* __restrict__ cnt,           // [NN][NT], zeroed
    int* __restrict__ eidx8,         // [NN][NT][8]
    int* __restrict__ ovf)           // [NT][NN][OVF]
{
    int part = blockIdx.x & (NPART - 1);
    int slab = blockIdx.x >> 3;
    int t = blockIdx.y;
    int e0 = slab * EPB + threadIdx.x * 4;
    if (e0 >= NE) return;
    const int* p = ei + (size_t)t * 2 * NE;
    i32x4 s4 = __builtin_nontemporal_load((const i32x4*)(p + e0));
    i32x4 d4 = __builtin_nontemporal_load((const i32x4*)(p + NE + e0));
    int lo = part * PSIZE;
    int hi = lo + PSIZE;
    #pragma unroll
    for (int k = 0; k < 4; ++k) {
        int src = s4[k];
        int dst = d4[k];
        if (dst >= lo && dst < hi) {
            int pos = atomicAdd(cnt + (size_t)dst * NT + t, 1);
            if (pos < 8)        eidx8[((size_t)dst * NT + t) * 8 + pos] = src;
            else if (pos < CAP) ovf[((size_t)t * NN + dst) * OVF + (pos - 8)] = src;
        }
    }
}

// ------------------------------------------------------------- aggregate ----
__global__ __launch_bounds__(256) void agg_k(
    const char* __restrict__ xb,     // [NN][256B] bf16 rows
    const int* __restrict__ cnt,     // [NN][NT]
    const int* __restrict__ eidx8,   // [NN][NT][8]
    const int* __restrict__ ovf,     // [NT][NN][OVF]
    char* __restrict__ aggb,         // [NT][nc][256B] chunk, swizzled
    int c0, int nc)
{
    int wid = (blockIdx.x * 256 + threadIdx.x) >> 6;
    int lane = threadIdx.x & 63;
    if (wid >= nc) return;
    const int n = c0 + wid;
    const bool live = (n < NN);

    int cntv = (live && lane < NT)
             ? __builtin_nontemporal_load(cnt + (size_t)n * NT + lane) : 0;
    int idxv = (live && lane < 56)
             ? __builtin_nontemporal_load(eidx8 + (size_t)n * 56 + lane) : 0;

    int r = wid & 127;
    int gran = (lane >> 2) ^ (r & 7);            // swizzle for ds_read_b128
    char* wbase = aggb + (size_t)(wid >> 7) * 32768 + r * 256
                + gran * 16 + (lane & 3) * 4;
    const size_t tstride = (size_t)nc * 256;

    for (int tp = 0; tp < NT; tp += 2) {
        int cA = __shfl(cntv, tp);
        int cB = (tp + 1 < NT) ? __shfl(cntv, tp + 1) : 0;
        int ccA = cA < CAP ? cA : CAP;
        int ccB = cB < CAP ? cB : CAP;
        int m = ccA > ccB ? ccA : ccB;

        f32x2 aA = {0.f, 0.f}, aB = {0.f, 0.f};
        for (int e = 0; e < m; e += 2) {         // 4 chains: 2 types x 2 edges
            unsigned vA0 = 0, vA1 = 0, vB0 = 0, vB1 = 0;
            if (e < ccA) {
                int s = (e < 8) ? __shfl(idxv, tp * 8 + e)
                                : __builtin_nontemporal_load(
                                      ovf + ((size_t)tp * NN + n) * OVF + (e - 8));
                vA0 = *(const unsigned*)(xb + (size_t)s * 256 + lane * 4);
            }
            if (e + 1 < ccA) {
                int s = (e + 1 < 8) ? __shfl(idxv, tp * 8 + e + 1)
                                    : __builtin_nontemporal_load(
                                          ovf + ((size_t)tp * NN + n) * OVF + (e - 7));
                vA1 = *(const unsigned*)(xb + (size_t)s * 256 + lane * 4);
            }
            if (e < ccB) {
                int s = (e < 8) ? __shfl(idxv, (tp + 1) * 8 + e)
                                : __builtin_nontemporal_load(
                                      ovf + ((size_t)(tp + 1) * NN + n) * OVF + (e - 8));
                vB0 = *(const unsigned*)(xb + (size_t)s * 256 + lane * 4);
            }
            if (e + 1 < ccB) {
                int s = (e + 1 < 8) ? __shfl(idxv, (tp + 1) * 8 + e + 1)
                                    : __builtin_nontemporal_load(
                                          ovf + ((size_t)(tp + 1) * NN + n) * OVF + (e - 7));
                vB1 = *(const unsigned*)(xb + (size_t)s * 256 + lane * 4);
            }
            aA += (f32x2){__uint_as_float(vA0 << 16), __uint_as_float(vA0 & 0xFFFF0000u)};
            aA += (f32x2){__uint_as_float(vA1 << 16), __uint_as_float(vA1 & 0xFFFF0000u)};
            aB += (f32x2){__uint_as_float(vB0 << 16), __uint_as_float(vB0 & 0xFFFF0000u)};
            aB += (f32x2){__uint_as_float(vB1 << 16), __uint_as_float(vB1 & 0xFFFF0000u)};
        }
        float sa = 1.0f / fmaxf((float)cA, 1.0f);   // mean folded pre-GEMM
        __builtin_nontemporal_store(pack_bf16x2(aA[0] * sa, aA[1] * sa),
                                    (unsigned*)(wbase + (size_t)tp * tstride));
        if (tp + 1 < NT) {
            float sb = 1.0f / fmaxf((float)cB, 1.0f);
            __builtin_nontemporal_store(pack_bf16x2(aB[0] * sb, aB[1] * sb),
                                        (unsigned*)(wbase + (size_t)(tp + 1) * tstride));
        }
    }
}

// ------------------------------------------------------------------ gemm ----
// 512 threads = 8 waves; wave w=(wy,wx): rows wy*32..+31, cols wx*64..+63.
// 14 pipeline steps (7 types x 2 K-halves of 64). Double-buffered 16KB tiles;
// stage(s+1) issued before MFMA(s); counted vmcnt so prefetch never drains.
__global__ __launch_bounds__(512) void gemm_k(
    const char* __restrict__ aggb, const char* __restrict__ WTb,
    const int* __restrict__ cnt, const float* __restrict__ bias,
    float* __restrict__ out, int c0, int nc)
{
    __shared__ char sA[2 * 16384];   // 32 KB: 2 bufs x (128 rows x 128B half)
    __shared__ char sW[2 * 16384];   // 32 KB
    int tid = threadIdx.x;
    int w = tid >> 6, lane = tid & 63;
    int wy = w >> 1, wx = w & 1;
    int n0 = c0 + blockIdx.x * 128;
    const size_t tstride = (size_t)nc * 256;
    const char* abase0 = aggb + (size_t)blockIdx.x * 32768;
    const int ro = (lane >> 3) * 256 + (lane & 7) * 16;   // 8 rows x 128B per 1KB chunk

    f32x4 acc[2][4];
    #pragma unroll
    for (int i = 0; i < 2; ++i)
        #pragma unroll
        for (int j = 0; j < 4; ++j) acc[i][j] = (f32x4)0.0f;

    // stage K-half step ss into buffer buf: 16KB A-half + 16KB W-half.
    // Per wave 2+2 chunks of 1KB; per-lane global src walks 8 rows x 128B.
    auto stage = [&](int buf, int ss) {
        int t = ss >> 1, h = ss & 1;
        const char* ab = abase0 + (size_t)t * tstride + h * 128;
        const char* wb = WTb + (size_t)t * 32768 + h * 128;
        #pragma unroll
        for (int i = 0; i < 2; ++i) {
            int ch = w * 2 + i;                       // 16 chunks = 128 rows
            __builtin_amdgcn_global_load_lds(
                (const __attribute__((address_space(1))) void*)(ab + ch * 2048 + ro),
                (__attribute__((address_space(3))) void*)(sA + buf * 16384 + ch * 1024),
                16, 0, 0);
            __builtin_amdgcn_global_load_lds(
                (const __attribute__((address_space(1))) void*)(wb + ch * 2048 + ro),
                (__attribute__((address_space(3))) void*)(sW + buf * 16384 + ch * 1024),
                16, 0, 0);
        }
    };

    stage(0, 0);
    #pragma unroll
    for (int s = 0; s < 14; ++s) {
        if (s < 13) {
            stage((s + 1) & 1, s + 1);                // prefetch next half-tile
            // wait only the CURRENT tile's 4 loads (oldest); barrier aligns waves
            asm volatile("s_waitcnt vmcnt(4)\n\ts_barrier" ::: "memory");
        } else {
            asm volatile("s_waitcnt vmcnt(0)\n\ts_barrier" ::: "memory");
        }
        const char* As = sA + (s & 1) * 16384;
        const char* Ws = sW + (s & 1) * 16384;
        #pragma unroll
        for (int cl = 0; cl < 2; ++cl) {
            int gsel = ((cl * 4 + (lane >> 4)) ^ (lane & 7)) << 4;
            bf16x8 A0 = *(const bf16x8*)(As + (wy * 32 + (lane & 15)) * 128 + gsel);
            bf16x8 A1 = *(const bf16x8*)(As + (wy * 32 + 16 + (lane & 15)) * 128 + gsel);
            #pragma unroll
            for (int nj = 0; nj < 4; ++nj) {
                bf16x8 B = *(const bf16x8*)(Ws + (wx * 64 + nj * 16 + (lane & 15)) * 128 + gsel);
                acc[0][nj] = __builtin_amdgcn_mfma_f32_16x16x32_bf16(A0, B, acc[0][nj], 0, 0, 0);
                acc[1][nj] = __builtin_amdgcn_mfma_f32_16x16x32_bf16(A1, B, acc[1][nj], 0, 0, 0);
            }
        }
        __builtin_amdgcn_s_barrier();   // readers done before buf is restaged
    }

    // epilogue: mean over types + per-type bias where cnt>0
    const float inv7 = 1.0f / (float)NT;
    #pragma unroll
    for (int mi = 0; mi < 2; ++mi) {
        #pragma unroll
        for (int v = 0; v < 4; ++v) {
            int n = n0 + wy * 32 + mi * 16 + (lane >> 4) * 4 + v;
            if (n >= NN) continue;
            float add[4] = {0.f, 0.f, 0.f, 0.f};
            for (int t = 0; t < NT; ++t) {
                if (cnt[(size_t)n * NT + t] > 0) {
                    #pragma unroll
                    for (int nj = 0; nj < 4; ++nj)
                        add[nj] += bias[(size_t)t * DD + wx * 64 + nj * 16 + (lane & 15)];
                }
            }
            #pragma unroll
            for (int nj = 0; nj < 4; ++nj)
                out[(size_t)n * DD + wx * 64 + nj * 16 + (lane & 15)]
                    = inv7 * (acc[mi][nj][v] + add[nj]);
        }
    }
}

// ---------------------------------------------------------------- launch ----
extern "C" void kernel_launch(void* const* d_in, const int* in_sizes, int n_in,
                              void* d_out, int out_size, void* d_ws, size_t ws_size,
                              hipStream_t stream) {
    const float* x  = (const float*)d_in[0];
    const int*   ei = (const int*)d_in[1];
    const float* W  = (const float*)d_in[2];
    const float* b  = (const float*)d_in[3];
    float* out = (float*)d_out;
    char* ws = (char*)d_ws;

    // fixed tables: 84.7 MB (layout proven R6/R8/R10)
    size_t off = 0;
    char* xb    = ws + off; off += (size_t)NN * 256;                  // 25.6 MB
    char* WTb   = ws + off; off += (size_t)NT * 128 * 256;            // 224 KB
    int*  eidx8 = (int*)(ws + off); off += (size_t)NN * NT * 8 * 4;   // 22.4 MB
    int*  cnti  = (int*)(ws + off); off += (size_t)NN * NT * 4;       //  2.8 MB
    int*  ovfp  = (int*)(ws + off); off += (size_t)NT * NN * OVF * 4; // 33.6 MB
    char* aggb  = ws + off;                                           // remainder

    size_t avail = (ws_size > off) ? (ws_size - off) : 0;
    int Nc = (int)(avail / ((size_t)NT * 256));
    Nc &= ~127;
    if (Nc < 128) Nc = 128;
    if (Nc > NROWS) Nc = NROWS;

    convx_k<<<(NN * DD / 8 + 255) / 256, 256, 0, stream>>>(x, (uint4*)xb);
    wconv_k<<<(NT * 128 + 3) / 4, 256, 0, stream>>>(W, WTb);
    hipMemsetAsync(cnti, 0, (size_t)NN * NT * 4, stream);
    fill_k<<<dim3(NSLAB * NPART, NT), 256, 0, stream>>>(ei, cnti, eidx8, ovfp);

    for (int c0 = 0; c0 < NN; c0 += Nc) {
        int nc = (NROWS - c0 < Nc) ? (NROWS - c0) : Nc;   // multiple of 128
        agg_k<<<nc / 4, 256, 0, stream>>>(xb, cnti, eidx8, ovfp, aggb, c0, nc);
        gemm_k<<<nc / 128, 512, 0, stream>>>(aggb, WTb, cnti, b, out, c0, nc);
    }
}

// Round 12
// 270.900 us; speedup vs baseline: 1.0241x; 1.0241x over previous
//
#include <hip/hip_runtime.h>

// SwitchGNN split pipeline (R10 base + branchless agg + high-occupancy gemm):
//  out = (1/7) * sum_t [ (segsum_t(x[src]) / max(cnt,1)) @ W_t + 1{cnt>0} b_t ]
// P0 convx_k: x -> bf16 rows (256B each); row NN is an all-zero pad row
// P1 wconv_k: W -> bf16, transposed [t][f][k], XOR-swizzled
// P2 init_k : eidx8 pre-filled with NN (pad index -> zero row, branchless agg)
// P3 fill_k : bucket edges by (dst,type), XCD-partitioned, nt edge reads
// P4 agg_k  : one wave per node; fast slots (<=8) gathered UNCONDITIONALLY
//             (pads hit the L1-hot zero row); rare c>8 tail via ovf.
//             64-row tile output layout for the 64-row gemm.
// P5 gemm_k : 64-row tiles, 256 thr, 24KB single-buffer LDS, BK=64 (14 steps),
//             launch_bounds(256,5) -> 5 blocks/CU so stage-drain stalls hide
//             in cross-block overlap (R11 showed explicit vmcnt pipelining
//             on 2 blocks/CU regresses).

constexpr int NN = 100000;
constexpr int NT = 7;
constexpr int NE = 250000;
constexpr int DD = 128;
constexpr int CAP = 20;           // max tracked edges per (n,t); P(Poisson(2.5)>20)~3e-12
constexpr int OVF = CAP - 8;      // overflow slots beyond the 8 fast slots
constexpr int NROWS = ((NN + 127) / 128) * 128;   // 100096 padded rows
constexpr int NPART = 8;                          // dst partitions = XCDs
constexpr int PSIZE = (NN + NPART - 1) / NPART;   // 12500 nodes per partition
constexpr int EPB = 1024;                         // edges per fill block
constexpr int NSLAB = (NE + EPB - 1) / EPB;       // 245 slabs

typedef short bf16x8 __attribute__((ext_vector_type(8)));
typedef float f32x4 __attribute__((ext_vector_type(4)));
typedef int   i32x4 __attribute__((ext_vector_type(4)));
typedef float fltx4 __attribute__((ext_vector_type(4)));

__device__ __forceinline__ unsigned pack_bf16x2(float lo, float hi) {
    unsigned a = __float_as_uint(lo), b = __float_as_uint(hi);
    unsigned al = (a + 0x7FFFu + ((a >> 16) & 1u)) >> 16;          // RNE
    unsigned bh = (b + 0x7FFFu + ((b >> 16) & 1u)) & 0xFFFF0000u;
    return al | bh;
}

// ---------------------------------------------------------------- conv x ----
__global__ __launch_bounds__(256) void convx_k(
    const float* __restrict__ x, uint4* __restrict__ xb)
{
    int id = blockIdx.x * 256 + threadIdx.x;
    const fltx4* src = (const fltx4*)x;
    fltx4 v0 = __builtin_nontemporal_load(src + (size_t)id * 2);
    fltx4 v1 = __builtin_nontemporal_load(src + (size_t)id * 2 + 1);
    uint4 o;
    o.x = pack_bf16x2(v0[0], v0[1]);
    o.y = pack_bf16x2(v0[2], v0[3]);
    o.z = pack_bf16x2(v1[0], v1[1]);
    o.w = pack_bf16x2(v1[2], v1[3]);
    xb[id] = o;
}

// ---------------------------------------------------------------- W conv ----
__global__ __launch_bounds__(256) void wconv_k(
    const float* __restrict__ W, char* __restrict__ WTb)
{
    int wid = (blockIdx.x * 256 + threadIdx.x) >> 6;
    int lane = threadIdx.x & 63;
    int t = wid >> 7, f = wid & 127;
    if (t >= NT) return;
    const float* Wt = W + (size_t)t * DD * DD;
    float w0 = Wt[(size_t)(2 * lane) * DD + f];
    float w1 = Wt[(size_t)(2 * lane + 1) * DD + f];
    int gran = (lane >> 2) ^ (f & 7);
    *(unsigned*)(WTb + (size_t)t * 32768 + f * 256 + gran * 16 + (lane & 3) * 4)
        = pack_bf16x2(w0, w1);
}

// ------------------------------------------------------------------ init ----
__global__ __launch_bounds__(256) void init_k(int* __restrict__ eidx8)
{
    int id = blockIdx.x * 256 + threadIdx.x;
    if (id < NN * NT * 8) eidx8[id] = NN;    // pad index -> zero row
}

// ------------------------------------------------------------------ fill ----
__global__ __launch_bounds__(256) void fill_k(
    const int* __restrict__ ei,      // [NT][2][NE]
    int* __restrict__ cnt,           // [NN][NT], zeroed
    int* __restrict__ eidx8,         // [NN][NT][8], pre-init to NN
    int* __restrict__ ovf)           // [NT][NN][OVF]
{
    int part = blockIdx.x & (NPART - 1);
    int slab = blockIdx.x >> 3;
    int t = blockIdx.y;
    int e0 = slab * EPB + threadIdx.x * 4;
    if (e0 >= NE) return;
    const int* p = ei + (size_t)t * 2 * NE;
    i32x4 s4 = __builtin_nontemporal_load((const i32x4*)(p + e0));
    i32x4 d4 = __builtin_nontemporal_load((const i32x4*)(p + NE + e0));
    int lo = part * PSIZE;
    int hi = lo + PSIZE;
    #pragma unroll
    for (int k = 0; k < 4; ++k) {
        int src = s4[k];
        int dst = d4[k];
        if (dst >= lo && dst < hi) {
            int pos = atomicAdd(cnt + (size_t)dst * NT + t, 1);
            if (pos < 8)        eidx8[((size_t)dst * NT + t) * 8 + pos] = src;
            else if (pos < CAP) ovf[((size_t)t * NN + dst) * OVF + (pos - 8)] = src;
        }
    }
}

// ------------------------------------------------------------- aggregate ----
// One wave per row (node n = c0 + wid). Lanes 0..6: per-type counts;
// lanes 0..55: fast-slot indices (padded with NN -> zero row). Fast loop is
// UNCONDITIONAL: 2 types x 2 slots = 4 gathers per iteration, no compares.
// Output: 64-row tiles, swizzled for ds_read_b128.
__global__ __launch_bounds__(256) void agg_k(
    const char* __restrict__ xb,     // [NN+1][256B] bf16 rows (row NN = zeros)
    const int* __restrict__ cnt,     // [NN][NT]
    const int* __restrict__ eidx8,   // [NN][NT][8]
    const int* __restrict__ ovf,     // [NT][NN][OVF]
    char* __restrict__ aggb,         // [NT][nc][256B], 64-row tiles, swizzled
    int c0, int nc)
{
    int wid = (blockIdx.x * 256 + threadIdx.x) >> 6;
    int lane = threadIdx.x & 63;
    if (wid >= nc) return;
    const int n = c0 + wid;
    const bool live = (n < NN);

    int cntv = (live && lane < NT)
             ? __builtin_nontemporal_load(cnt + (size_t)n * NT + lane) : 0;
    int idxv = (live && lane < 56)
             ? __builtin_nontemporal_load(eidx8 + (size_t)n * 56 + lane) : NN;

    int gran = (lane >> 2) ^ (wid & 7);          // swizzle for ds_read_b128
    char* wbase = aggb + (size_t)(wid >> 6) * 16384 + (wid & 63) * 256
                + gran * 16 + (lane & 3) * 4;
    const size_t tstride = (size_t)nc * 256;

    for (int tp = 0; tp < NT; tp += 2) {
        int cA = __shfl(cntv, tp);
        int cB = (tp + 1 < NT) ? __shfl(cntv, tp + 1) : 0;
        int ccA = cA < CAP ? cA : CAP;
        int ccB = cB < CAP ? cB : CAP;
        int m = ccA > ccB ? ccA : ccB;
        int mm = m < 8 ? m : 8;

        float a0 = 0.f, a1 = 0.f, b0 = 0.f, b1 = 0.f;
        for (int e = 0; e < mm; e += 2) {        // branchless: pads add zero
            int sA0 = __shfl(idxv, tp * 8 + e);
            int sA1 = __shfl(idxv, tp * 8 + e + 1);
            int sB0 = __shfl(idxv, tp * 8 + 8 + e);
            int sB1 = __shfl(idxv, tp * 8 + 9 + e);
            unsigned vA0 = *(const unsigned*)(xb + (size_t)sA0 * 256 + lane * 4);
            unsigned vA1 = *(const unsigned*)(xb + (size_t)sA1 * 256 + lane * 4);
            unsigned vB0 = *(const unsigned*)(xb + (size_t)sB0 * 256 + lane * 4);
            unsigned vB1 = *(const unsigned*)(xb + (size_t)sB1 * 256 + lane * 4);
            a0 += __uint_as_float(vA0 << 16) + __uint_as_float(vA1 << 16);
            a1 += __uint_as_float(vA0 & 0xFFFF0000u) + __uint_as_float(vA1 & 0xFFFF0000u);
            b0 += __uint_as_float(vB0 << 16) + __uint_as_float(vB1 << 16);
            b1 += __uint_as_float(vB0 & 0xFFFF0000u) + __uint_as_float(vB1 & 0xFFFF0000u);
        }
        if (m > 8) {                             // rare tail (P ~ 1e-3 per node)
            for (int e = 8; e < m; ++e) {
                if (e < ccA) {
                    int s = __builtin_nontemporal_load(
                        ovf + ((size_t)tp * NN + n) * OVF + (e - 8));
                    unsigned v = *(const unsigned*)(xb + (size_t)s * 256 + lane * 4);
                    a0 += __uint_as_float(v << 16);
                    a1 += __uint_as_float(v & 0xFFFF0000u);
                }
                if (e < ccB) {
                    int s = __builtin_nontemporal_load(
                        ovf + ((size_t)(tp + 1) * NN + n) * OVF + (e - 8));
                    unsigned v = *(const unsigned*)(xb + (size_t)s * 256 + lane * 4);
                    b0 += __uint_as_float(v << 16);
                    b1 += __uint_as_float(v & 0xFFFF0000u);
                }
            }
        }
        float sa = 1.0f / fmaxf((float)cA, 1.0f);   // mean folded pre-GEMM
        *(unsigned*)(wbase + (size_t)tp * tstride) = pack_bf16x2(a0 * sa, a1 * sa);
        if (tp + 1 < NT) {
            float sb = 1.0f / fmaxf((float)cB, 1.0f);
            *(unsigned*)(wbase + (size_t)(tp + 1) * tstride) = pack_bf16x2(b0 * sb, b1 * sb);
        }
    }
}

// ------------------------------------------------------------------ gemm ----
// 256 threads = 4 waves; wave w=(wy,wx): rows wy*32..+31, cols wx*64..+63.
// 14 steps (7 types x 2 K-halves of 64), single 24KB buffer, 5 blocks/CU.
__global__ __launch_bounds__(256, 5) void gemm_k(
    const char* __restrict__ aggb, const char* __restrict__ WTb,
    const int* __restrict__ cnt, const float* __restrict__ bias,
    float* __restrict__ out, int c0, int nc)
{
    __shared__ char sA[64 * 128];    //  8 KB: 64 rows x 128B K-half
    __shared__ char sW[128 * 128];   // 16 KB: 128 f-rows x 128B K-half
    int tid = threadIdx.x;
    int w = tid >> 6, lane = tid & 63;
    int wy = w >> 1, wx = w & 1;
    int n0 = c0 + blockIdx.x * 64;
    const size_t tstride = (size_t)nc * 256;
    const char* abase0 = aggb + (size_t)blockIdx.x * 16384;
    const int ro = (lane >> 3) * 256 + (lane & 7) * 16;  // 8 rows x 128B / 1KB chunk

    f32x4 acc[2][4];
    #pragma unroll
    for (int i = 0; i < 2; ++i)
        #pragma unroll
        for (int j = 0; j < 4; ++j) acc[i][j] = (f32x4)0.0f;

    for (int s = 0; s < 14; ++s) {
        int t = s >> 1, h = s & 1;
        __syncthreads();   // prev step's readers done before restage
        const char* ab = abase0 + (size_t)t * tstride + h * 128;
        const char* wb = WTb + (size_t)t * 32768 + h * 128;
        #pragma unroll
        for (int i = 0; i < 2; ++i) {            // A: 8 chunks of 1KB
            int ch = w * 2 + i;
            __builtin_amdgcn_global_load_lds(
                (const __attribute__((address_space(1))) void*)(ab + ch * 2048 + ro),
                (__attribute__((address_space(3))) void*)(sA + ch * 1024), 16, 0, 0);
        }
        #pragma unroll
        for (int i = 0; i < 4; ++i) {            // W: 16 chunks of 1KB
            int ch = w * 4 + i;
            __builtin_amdgcn_global_load_lds(
                (const __attribute__((address_space(1))) void*)(wb + ch * 2048 + ro),
                (__attribute__((address_space(3))) void*)(sW + ch * 1024), 16, 0, 0);
        }
        __syncthreads();   // compiler drains vmcnt before barrier

        #pragma unroll
        for (int cl = 0; cl < 2; ++cl) {
            int gsel = ((cl * 4 + (lane >> 4)) ^ (lane & 7)) << 4;
            bf16x8 A0 = *(const bf16x8*)(sA + (wy * 32 + (lane & 15)) * 128 + gsel);
            bf16x8 A1 = *(const bf16x8*)(sA + (wy * 32 + 16 + (lane & 15)) * 128 + gsel);
            #pragma unroll
            for (int nj = 0; nj < 4; ++nj) {
                bf16x8 B = *(const bf16x8*)(sW + (wx * 64 + nj * 16 + (lane & 15)) * 128 + gsel);
                acc[0][nj] = __builtin_amdgcn_mfma_f32_16x16x32_bf16(A0, B, acc[0][nj], 0, 0, 0);
                acc[1][nj] = __builtin_amdgcn_mfma_f32_16x16x32_bf16(A1, B, acc[1][nj], 0, 0, 0);
            }
        }
    }

    // epilogue: mean over types + per-type bias where cnt>0
    const float inv7 = 1.0f / (float)NT;
    #pragma unroll
    for (int mi = 0; mi < 2; ++mi) {
        #pragma unroll
        for (int v = 0; v < 4; ++v) {
            int n = n0 + wy * 32 + mi * 16 + (lane >> 4) * 4 + v;
            if (n >= NN) continue;
            float add[4] = {0.f, 0.f, 0.f, 0.f};
            for (int t = 0; t < NT; ++t) {
                if (cnt[(size_t)n * NT + t] > 0) {
                    #pragma unroll
                    for (int nj = 0; nj < 4; ++nj)
                        add[nj] += bias[(size_t)t * DD + wx * 64 + nj * 16 + (lane & 15)];
                }
            }
            #pragma unroll
            for (int nj = 0; nj < 4; ++nj)
                out[(size_t)n * DD + wx * 64 + nj * 16 + (lane & 15)]
                    = inv7 * (acc[mi][nj][v] + add[nj]);
        }
    }
}

// ---------------------------------------------------------------- launch ----
extern "C" void kernel_launch(void* const* d_in, const int* in_sizes, int n_in,
                              void* d_out, int out_size, void* d_ws, size_t ws_size,
                              hipStream_t stream) {
    const float* x  = (const float*)d_in[0];
    const int*   ei = (const int*)d_in[1];
    const float* W  = (const float*)d_in[2];
    const float* b  = (const float*)d_in[3];
    float* out = (float*)d_out;
    char* ws = (char*)d_ws;

    // fixed tables: ~84.9 MB (layout proven R10/R11; xb grows by 1 pad row)
    size_t off = 0;
    char* xb    = ws + off; off += (size_t)(NN + 1) * 256;            // 25.6 MB
    char* WTb   = ws + off; off += (size_t)NT * 128 * 256;            // 224 KB
    int*  eidx8 = (int*)(ws + off); off += (size_t)NN * NT * 8 * 4;   // 22.4 MB
    int*  cnti  = (int*)(ws + off); off += (size_t)NN * NT * 4;       //  2.8 MB
    int*  ovfp  = (int*)(ws + off); off += (size_t)NT * NN * OVF * 4; // 33.6 MB
    char* aggb  = ws + off;                                           // remainder

    size_t avail = (ws_size > off) ? (ws_size - off) : 0;
    int Nc = (int)(avail / ((size_t)NT * 256));
    Nc &= ~127;
    if (Nc < 128) Nc = 128;
    if (Nc > NROWS) Nc = NROWS;

    convx_k<<<(NN * DD / 8 + 255) / 256, 256, 0, stream>>>(x, (uint4*)xb);
    hipMemsetAsync(xb + (size_t)NN * 256, 0, 256, stream);   // zero pad row
    wconv_k<<<(NT * 128 + 3) / 4, 256, 0, stream>>>(W, WTb);
    hipMemsetAsync(cnti, 0, (size_t)NN * NT * 4, stream);
    init_k<<<(NN * NT * 8 + 255) / 256, 256, 0, stream>>>(eidx8);
    fill_k<<<dim3(NSLAB * NPART, NT), 256, 0, stream>>>(ei, cnti, eidx8, ovfp);

    for (int c0 = 0; c0 < NN; c0 += Nc) {
        int nc = (NROWS - c0 < Nc) ? (NROWS - c0) : Nc;   // multiple of 128
        agg_k<<<nc / 4, 256, 0, stream>>>(xb, cnti, eidx8, ovfp, aggb, c0, nc);
        gemm_k<<<nc / 64, 256, 0, stream>>>(aggb, WTb, cnti, b, out, c0, nc);
    }
}

// Round 13
// 257.360 us; speedup vs baseline: 1.0780x; 1.0526x over previous
//
#include <hip/hip_runtime.h>

// SwitchGNN split pipeline (R13: per-node bucket + in-wave type sort):
//  out = (1/7) * sum_t [ (segsum_t(x[src]) / max(cnt,1)) @ W_t + 1{cnt>0} b_t ]
// P0 convx_k: x -> bf16 rows (256B each); row NN is an all-zero pad row
// P1 wconv_k: W -> bf16, transposed [t][f][k], XOR-swizzled
// P2 fill_k : ONE bucket per node (64 slots, val = src|t<<17), 1 atomic +
//             1 store per edge; XCD-partitioned dst ranges, nt edge reads
// P3 agg_k  : one wave per node: 8 ballots -> exact per-type counts,
//             popc-rank + ds_permute sorts edges by type in-register;
//             2-type x 2-edge chains with EXACT bounds (pads -> zero row);
//             emits swizzled bf16 rows + per-node bias bitmask
// P4 gemm_k : R10's 128-row 8-wave BK=128 t-loop (proven best: R11 pipelining
//             and R12 64-row/5-per-CU both regressed), bias via bitmask.

constexpr int NN = 100000;
constexpr int NT = 7;
constexpr int NE = 250000;
constexpr int DD = 128;
constexpr int NROWS = ((NN + 127) / 128) * 128;   // 100096 padded rows
constexpr int NPART = 8;                          // dst partitions = XCDs
constexpr int PSIZE = (NN + NPART - 1) / NPART;   // 12500 nodes per partition
constexpr int EPB = 1024;                         // edges per fill block
constexpr int NSLAB = (NE + EPB - 1) / EPB;       // 245 slabs

typedef short bf16x8 __attribute__((ext_vector_type(8)));
typedef float f32x4 __attribute__((ext_vector_type(4)));
typedef int   i32x4 __attribute__((ext_vector_type(4)));
typedef float fltx4 __attribute__((ext_vector_type(4)));

__device__ __forceinline__ unsigned pack_bf16x2(float lo, float hi) {
    unsigned a = __float_as_uint(lo), b = __float_as_uint(hi);
    unsigned al = (a + 0x7FFFu + ((a >> 16) & 1u)) >> 16;          // RNE
    unsigned bh = (b + 0x7FFFu + ((b >> 16) & 1u)) & 0xFFFF0000u;
    return al | bh;
}

// ---------------------------------------------------------------- conv x ----
__global__ __launch_bounds__(256) void convx_k(
    const float* __restrict__ x, uint4* __restrict__ xb)
{
    int id = blockIdx.x * 256 + threadIdx.x;
    const fltx4* src = (const fltx4*)x;
    fltx4 v0 = __builtin_nontemporal_load(src + (size_t)id * 2);
    fltx4 v1 = __builtin_nontemporal_load(src + (size_t)id * 2 + 1);
    uint4 o;
    o.x = pack_bf16x2(v0[0], v0[1]);
    o.y = pack_bf16x2(v0[2], v0[3]);
    o.z = pack_bf16x2(v1[0], v1[1]);
    o.w = pack_bf16x2(v1[2], v1[3]);
    xb[id] = o;
}

// ---------------------------------------------------------------- W conv ----
__global__ __launch_bounds__(256) void wconv_k(
    const float* __restrict__ W, char* __restrict__ WTb)
{
    int wid = (blockIdx.x * 256 + threadIdx.x) >> 6;
    int lane = threadIdx.x & 63;
    int t = wid >> 7, f = wid & 127;
    if (t >= NT) return;
    const float* Wt = W + (size_t)t * DD * DD;
    float w0 = Wt[(size_t)(2 * lane) * DD + f];
    float w1 = Wt[(size_t)(2 * lane + 1) * DD + f];
    int gran = (lane >> 2) ^ (f & 7);
    *(unsigned*)(WTb + (size_t)t * 32768 + f * 256 + gran * 16 + (lane & 3) * 4)
        = pack_bf16x2(w0, w1);
}

// ------------------------------------------------------------------ fill ----
// One bucket per node: slot val = src | (t<<17). 1 atomic + 1 store per edge.
__global__ __launch_bounds__(256) void fill_k(
    const int* __restrict__ ei,      // [NT][2][NE]
    int* __restrict__ cntT,          // [NN], zeroed
    int* __restrict__ eslots)        // [NN][64]
{
    int part = blockIdx.x & (NPART - 1);
    int slab = blockIdx.x >> 3;
    int t = blockIdx.y;
    int e0 = slab * EPB + threadIdx.x * 4;
    if (e0 >= NE) return;
    const int* p = ei + (size_t)t * 2 * NE;
    i32x4 s4 = __builtin_nontemporal_load((const i32x4*)(p + e0));
    i32x4 d4 = __builtin_nontemporal_load((const i32x4*)(p + NE + e0));
    int lo = part * PSIZE;
    int hi = lo + PSIZE;
    int tv = t << 17;
    #pragma unroll
    for (int k = 0; k < 4; ++k) {
        int src = s4[k];
        int dst = d4[k];
        if (dst >= lo && dst < hi) {
            int pos = atomicAdd(cntT + dst, 1);
            if (pos < 64) eslots[(size_t)dst * 64 + pos] = src | tv;
        }
    }
}

// ------------------------------------------------------------- aggregate ----
// One wave per row (node n = c0 + wid). Exact per-type counts via ballots;
// in-register type sort via popc-rank + ds_permute; 4-chain gather loop with
// exact bounds (pads select lane 63 = zero-row index). Lane holds features
// 2*lane, 2*lane+1.
__global__ __launch_bounds__(256) void agg_k(
    const char* __restrict__ xb,     // [NN+1][256B] bf16 rows (row NN = zeros)
    const int* __restrict__ cntT,    // [NN]
    const int* __restrict__ eslots,  // [NN][64]
    char* __restrict__ aggb,         // [NT][nc][256B], 128-row tiles, swizzled
    unsigned char* __restrict__ bmask, // [NN] per-type has-edges bits
    int c0, int nc)
{
    int wid = (blockIdx.x * 256 + threadIdx.x) >> 6;
    int lane = threadIdx.x & 63;
    if (wid >= nc) return;
    const int n = c0 + wid;
    const bool live = (n < NN);

    int total = live ? cntT[n] : 0;
    if (total > 64) total = 64;      // P(Poisson(17.5)>64) ~ 1e-19
    int val = (live && lane < total)
            ? __builtin_nontemporal_load(eslots + (size_t)n * 64 + lane) : 0;
    int mytype = (lane < total) ? ((val >> 17) & 7) : 7;

    // exact per-type counts + segment starts (wave-uniform)
    unsigned long long bal[8];
    #pragma unroll
    for (int t = 0; t < 8; ++t) bal[t] = __ballot(mytype == t);
    int ct[7], st[7];
    {
        int s = 0;
        #pragma unroll
        for (int t = 0; t < 7; ++t) { st[t] = s; ct[t] = (int)__popcll(bal[t]); s += ct[t]; }
    }

    // rank = edges of smaller type before me + my intra-type rank (static idx)
    unsigned long long before = 0, mine = bal[7];
    #pragma unroll
    for (int t = 0; t < 7; ++t) {
        before |= (mytype > t) ? bal[t] : 0ull;
        mine = (mytype == t) ? bal[t] : mine;
    }
    int rank = (int)__popcll(before)
             + (int)__popcll(mine & ((1ull << lane) - 1ull));
    int sorted = __builtin_amdgcn_ds_permute(rank << 2, val);
    int val2 = (lane < total) ? (sorted & 0x1FFFF) : NN;   // pads -> zero row

    int gran = (lane >> 2) ^ (wid & 7);          // swizzle for ds_read_b128
    char* wbase = aggb + (size_t)(wid >> 7) * 32768 + (size_t)(wid & 127) * 256
                + gran * 16 + (lane & 3) * 4;
    const size_t tstride = (size_t)nc * 256;
    unsigned msk = 0;

    #pragma unroll
    for (int tp = 0; tp < 7; tp += 2) {
        const int cA = ct[tp], stA = st[tp];
        const int cB = (tp + 1 < 7) ? ct[tp + 1] : 0;
        const int stB = (tp + 1 < 7) ? st[tp + 1] : 0;
        int m2 = cA > cB ? cA : cB;

        float a0 = 0.f, a1 = 0.f, b0 = 0.f, b1 = 0.f;
        for (int e = 0; e < m2; e += 2) {        // exact bounds; pads = lane 63
            int iA0 = (e < cA)     ? stA + e     : 63;
            int iA1 = (e + 1 < cA) ? stA + e + 1 : 63;
            int iB0 = (e < cB)     ? stB + e     : 63;
            int iB1 = (e + 1 < cB) ? stB + e + 1 : 63;
            int sA0 = __shfl(val2, iA0);
            int sA1 = __shfl(val2, iA1);
            int sB0 = __shfl(val2, iB0);
            int sB1 = __shfl(val2, iB1);
            unsigned vA0 = *(const unsigned*)(xb + (size_t)sA0 * 256 + lane * 4);
            unsigned vA1 = *(const unsigned*)(xb + (size_t)sA1 * 256 + lane * 4);
            unsigned vB0 = *(const unsigned*)(xb + (size_t)sB0 * 256 + lane * 4);
            unsigned vB1 = *(const unsigned*)(xb + (size_t)sB1 * 256 + lane * 4);
            a0 += __uint_as_float(vA0 << 16) + __uint_as_float(vA1 << 16);
            a1 += __uint_as_float(vA0 & 0xFFFF0000u) + __uint_as_float(vA1 & 0xFFFF0000u);
            b0 += __uint_as_float(vB0 << 16) + __uint_as_float(vB1 << 16);
            b1 += __uint_as_float(vB0 & 0xFFFF0000u) + __uint_as_float(vB1 & 0xFFFF0000u);
        }
        float sa = 1.0f / fmaxf((float)cA, 1.0f);   // mean folded pre-GEMM
        *(unsigned*)(wbase + (size_t)tp * tstride) = pack_bf16x2(a0 * sa, a1 * sa);
        msk |= (cA > 0) ? (1u << tp) : 0u;
        if (tp + 1 < 7) {
            float sb = 1.0f / fmaxf((float)cB, 1.0f);
            *(unsigned*)(wbase + (size_t)(tp + 1) * tstride) = pack_bf16x2(b0 * sb, b1 * sb);
            msk |= (cB > 0) ? (1u << (tp + 1)) : 0u;
        }
    }
    if (live && lane == 0) bmask[n] = (unsigned char)msk;
}

// ------------------------------------------------------------------ gemm ----
// R10 structure: 512 threads = 8 waves; wave w=(wy,wx): rows wy*32..+31,
// cols wx*64..+63. K-loop over 7 types (K=896, BK=128). Bias via bmask.
__global__ __launch_bounds__(512) void gemm_k(
    const char* __restrict__ aggb, const char* __restrict__ WTb,
    const unsigned char* __restrict__ bmask, const float* __restrict__ bias,
    float* __restrict__ out, int c0, int nc)
{
    __shared__ char sA[128 * 256];   // 32 KB
    __shared__ char sW[128 * 256];   // 32 KB
    int tid = threadIdx.x;
    int w = tid >> 6, lane = tid & 63;
    int wy = w >> 1, wx = w & 1;
    int n0 = c0 + blockIdx.x * 128;
    const size_t tstride = (size_t)nc * 256;

    f32x4 acc[2][4];
    #pragma unroll
    for (int i = 0; i < 2; ++i)
        #pragma unroll
        for (int j = 0; j < 4; ++j) acc[i][j] = (f32x4)0.0f;

    for (int t = 0; t < NT; ++t) {
        __syncthreads();   // prev MFMA readers done before restage
        const char* asrc = aggb + (size_t)t * tstride + (size_t)blockIdx.x * 32768;
        const char* wsrc = WTb + (size_t)t * 32768;
        #pragma unroll
        for (int i = 0; i < 4; ++i) {
            int ch = w * 4 + i;     // 32 chunks x 1KB each
            __builtin_amdgcn_global_load_lds(
                (const __attribute__((address_space(1))) void*)(asrc + ch * 1024 + lane * 16),
                (__attribute__((address_space(3))) void*)(sA + ch * 1024), 16, 0, 0);
            __builtin_amdgcn_global_load_lds(
                (const __attribute__((address_space(1))) void*)(wsrc + ch * 1024 + lane * 16),
                (__attribute__((address_space(3))) void*)(sW + ch * 1024), 16, 0, 0);
        }
        __syncthreads();   // compiler drains vmcnt before barrier

        #pragma unroll
        for (int c = 0; c < 4; ++c) {
            int gsel = ((c * 4 + (lane >> 4)) ^ (lane & 7)) << 4;
            bf16x8 A0 = *(const bf16x8*)(sA + (wy * 32 + (lane & 15)) * 256 + gsel);
            bf16x8 A1 = *(const bf16x8*)(sA + (wy * 32 + 16 + (lane & 15)) * 256 + gsel);
            #pragma unroll
            for (int nj = 0; nj < 4; ++nj) {
                bf16x8 B = *(const bf16x8*)(sW + (wx * 64 + nj * 16 + (lane & 15)) * 256 + gsel);
                acc[0][nj] = __builtin_amdgcn_mfma_f32_16x16x32_bf16(A0, B, acc[0][nj], 0, 0, 0);
                acc[1][nj] = __builtin_amdgcn_mfma_f32_16x16x32_bf16(A1, B, acc[1][nj], 0, 0, 0);
            }
        }
    }

    // epilogue: mean over types + per-type bias where the node has edges
    const float inv7 = 1.0f / (float)NT;
    #pragma unroll
    for (int mi = 0; mi < 2; ++mi) {
        #pragma unroll
        for (int v = 0; v < 4; ++v) {
            int n = n0 + wy * 32 + mi * 16 + (lane >> 4) * 4 + v;
            if (n >= NN) continue;
            unsigned mk = bmask[n];
            float add[4] = {0.f, 0.f, 0.f, 0.f};
            #pragma unroll
            for (int t = 0; t < NT; ++t) {
                if ((mk >> t) & 1u) {
                    #pragma unroll
                    for (int nj = 0; nj < 4; ++nj)
                        add[nj] += bias[(size_t)t * DD + wx * 64 + nj * 16 + (lane & 15)];
                }
            }
            #pragma unroll
            for (int nj = 0; nj < 4; ++nj)
                out[(size_t)n * DD + wx * 64 + nj * 16 + (lane & 15)]
                    = inv7 * (acc[mi][nj][v] + add[nj]);
        }
    }
}

// ---------------------------------------------------------------- launch ----
extern "C" void kernel_launch(void* const* d_in, const int* in_sizes, int n_in,
                              void* d_out, int out_size, void* d_ws, size_t ws_size,
                              hipStream_t stream) {
    const float* x  = (const float*)d_in[0];
    const int*   ei = (const int*)d_in[1];
    const float* W  = (const float*)d_in[2];
    const float* b  = (const float*)d_in[3];
    float* out = (float*)d_out;
    char* ws = (char*)d_ws;

    // fixed tables: ~52 MB; aggb 179.4 MB -> total ~231 MB (ws proven >= 264)
    size_t off = 0;
    char* xb     = ws + off; off += (size_t)(NN + 1) * 256;            // 25.6 MB
    char* WTb    = ws + off; off += (size_t)NT * 128 * 256;            // 224 KB
    int*  eslots = (int*)(ws + off); off += (size_t)NN * 64 * 4;       // 25.6 MB
    int*  cntT   = (int*)(ws + off); off += (size_t)NN * 4;            // 400 KB
    unsigned char* bmask = (unsigned char*)(ws + off); off += (size_t)NN; // 100 KB
    off = (off + 255) & ~(size_t)255;
    char* aggb   = ws + off;                                           // remainder

    size_t avail = (ws_size > off) ? (ws_size - off) : 0;
    int Nc = (int)(avail / ((size_t)NT * 256));
    Nc &= ~127;
    if (Nc < 128) Nc = 128;
    if (Nc > NROWS) Nc = NROWS;

    convx_k<<<(NN * DD / 8 + 255) / 256, 256, 0, stream>>>(x, (uint4*)xb);
    hipMemsetAsync(xb + (size_t)NN * 256, 0, 256, stream);   // zero pad row
    wconv_k<<<(NT * 128 + 3) / 4, 256, 0, stream>>>(W, WTb);
    hipMemsetAsync(cntT, 0, (size_t)NN * 4, stream);
    fill_k<<<dim3(NSLAB * NPART, NT), 256, 0, stream>>>(ei, cntT, eslots);

    for (int c0 = 0; c0 < NN; c0 += Nc) {
        int nc = (NROWS - c0 < Nc) ? (NROWS - c0) : Nc;   // multiple of 128
        agg_k<<<nc / 4, 256, 0, stream>>>(xb, cntT, eslots, aggb, bmask, c0, nc);
        gemm_k<<<nc / 128, 512, 0, stream>>>(aggb, WTb, bmask, b, out, c0, nc);
    }
}

// Round 16
// 255.284 us; speedup vs baseline: 1.0868x; 1.0081x over previous
//
#include <hip/hip_runtime.h>

// SwitchGNN split pipeline (R16 = R15 type-split agg, shfl-discipline fixed):
//  out = (1/7) * sum_t [ (segsum_t(x[src]) / max(cnt,1)) @ W_t + 1{cnt>0} b_t ]
// P0 convx_k: x -> bf16 rows (256B each); row NN is an all-zero pad row
// P1 wconv_k: W -> bf16, transposed [t][f][k], XOR-swizzled
// P2 fill_k : ONE bucket per node (64 slots, val = src|t<<17)
// P3 agg_k  : one wave per node: ballot counts + popc-rank + ds_permute sort
//             (R13-proven). Half-wave TYPE split: lanes 0-31 own type tp,
//             lanes 32-63 own tp+1; b64 gathers (lane h = features 4h..4h+3).
//             CRITICAL: loop bound is wave-uniform max(cA,cB) and every
//             __shfl executes with ALL lanes active (CDNA ds_bpermute from an
//             exec-masked source lane is UNDEFINED -- R14/R15's bug); pads
//             select the zero row AFTER the shfl.
// P4 gemm_k : R10's 128-row 8-wave BK=128 t-loop (proven best), bias bitmask.

constexpr int NN = 100000;
constexpr int NT = 7;
constexpr int NE = 250000;
constexpr int DD = 128;
constexpr int NROWS = ((NN + 127) / 128) * 128;   // 100096 padded rows
constexpr int NPART = 8;                          // dst partitions = XCDs
constexpr int PSIZE = (NN + NPART - 1) / NPART;   // 12500 nodes per partition
constexpr int EPB = 1024;                         // edges per fill block
constexpr int NSLAB = (NE + EPB - 1) / EPB;       // 245 slabs

typedef short bf16x8 __attribute__((ext_vector_type(8)));
typedef float f32x4 __attribute__((ext_vector_type(4)));
typedef int   i32x4 __attribute__((ext_vector_type(4)));
typedef float fltx4 __attribute__((ext_vector_type(4)));

__device__ __forceinline__ unsigned pack_bf16x2(float lo, float hi) {
    unsigned a = __float_as_uint(lo), b = __float_as_uint(hi);
    unsigned al = (a + 0x7FFFu + ((a >> 16) & 1u)) >> 16;          // RNE
    unsigned bh = (b + 0x7FFFu + ((b >> 16) & 1u)) & 0xFFFF0000u;
    return al | bh;
}

// ---------------------------------------------------------------- conv x ----
__global__ __launch_bounds__(256) void convx_k(
    const float* __restrict__ x, uint4* __restrict__ xb)
{
    int id = blockIdx.x * 256 + threadIdx.x;
    const fltx4* src = (const fltx4*)x;
    fltx4 v0 = __builtin_nontemporal_load(src + (size_t)id * 2);
    fltx4 v1 = __builtin_nontemporal_load(src + (size_t)id * 2 + 1);
    uint4 o;
    o.x = pack_bf16x2(v0[0], v0[1]);
    o.y = pack_bf16x2(v0[2], v0[3]);
    o.z = pack_bf16x2(v1[0], v1[1]);
    o.w = pack_bf16x2(v1[2], v1[3]);
    xb[id] = o;
}

// ---------------------------------------------------------------- W conv ----
__global__ __launch_bounds__(256) void wconv_k(
    const float* __restrict__ W, char* __restrict__ WTb)
{
    int wid = (blockIdx.x * 256 + threadIdx.x) >> 6;
    int lane = threadIdx.x & 63;
    int t = wid >> 7, f = wid & 127;
    if (t >= NT) return;
    const float* Wt = W + (size_t)t * DD * DD;
    float w0 = Wt[(size_t)(2 * lane) * DD + f];
    float w1 = Wt[(size_t)(2 * lane + 1) * DD + f];
    int gran = (lane >> 2) ^ (f & 7);
    *(unsigned*)(WTb + (size_t)t * 32768 + f * 256 + gran * 16 + (lane & 3) * 4)
        = pack_bf16x2(w0, w1);
}

// ------------------------------------------------------------------ fill ----
__global__ __launch_bounds__(256) void fill_k(
    const int* __restrict__ ei,      // [NT][2][NE]
    int* __restrict__ cntT,          // [NN], zeroed
    int* __restrict__ eslots)        // [NN][64]
{
    int part = blockIdx.x & (NPART - 1);
    int slab = blockIdx.x >> 3;
    int t = blockIdx.y;
    int e0 = slab * EPB + threadIdx.x * 4;
    if (e0 >= NE) return;
    const int* p = ei + (size_t)t * 2 * NE;
    i32x4 s4 = __builtin_nontemporal_load((const i32x4*)(p + e0));
    i32x4 d4 = __builtin_nontemporal_load((const i32x4*)(p + NE + e0));
    int lo = part * PSIZE;
    int hi = lo + PSIZE;
    int tv = t << 17;
    #pragma unroll
    for (int k = 0; k < 4; ++k) {
        int src = s4[k];
        int dst = d4[k];
        if (dst >= lo && dst < hi) {
            int pos = atomicAdd(cntT + dst, 1);
            if (pos < 64) eslots[(size_t)dst * 64 + pos] = src | tv;
        }
    }
}

// ------------------------------------------------------------- aggregate ----
__global__ __launch_bounds__(256) void agg_k(
    const char* __restrict__ xb,     // [NN+1][256B] bf16 rows (row NN = zeros)
    const int* __restrict__ cntT,    // [NN]
    const int* __restrict__ eslots,  // [NN][64]
    char* __restrict__ aggb,         // [NT][nc][256B], 128-row tiles, swizzled
    unsigned char* __restrict__ bmask, // [NN] per-type has-edges bits
    int c0, int nc)
{
    int wid = (blockIdx.x * 256 + threadIdx.x) >> 6;
    int lane = threadIdx.x & 63;
    if (wid >= nc) return;
    const int n = c0 + wid;
    const bool live = (n < NN);

    int total = live ? cntT[n] : 0;
    if (total > 64) total = 64;      // P(Poisson(17.5)>64) ~ 1e-19
    int val = (live && lane < total)
            ? __builtin_nontemporal_load(eslots + (size_t)n * 64 + lane) : 0;
    int mytype = (lane < total) ? ((val >> 17) & 7) : 7;

    // exact per-type counts + segment starts (wave-uniform)
    unsigned long long bal[8];
    #pragma unroll
    for (int t = 0; t < 8; ++t) bal[t] = __ballot(mytype == t);
    int ct[7], st[7];
    {
        int s = 0;
        #pragma unroll
        for (int t = 0; t < 7; ++t) { st[t] = s; ct[t] = (int)__popcll(bal[t]); s += ct[t]; }
    }

    // rank = edges of smaller type before me + my intra-type rank (static idx)
    unsigned long long before = 0, mine = bal[7];
    #pragma unroll
    for (int t = 0; t < 7; ++t) {
        before |= (mytype > t) ? bal[t] : 0ull;
        mine = (mytype == t) ? bal[t] : mine;
    }
    int rank = (int)__popcll(before)
             + (int)__popcll(mine & ((1ull << lane) - 1ull));
    int sorted = __builtin_amdgcn_ds_permute(rank << 2, val);
    int val2 = (lane < total) ? (sorted & 0x1FFFF) : NN;   // pads -> zero row

    const int h = lane & 31;         // feature group 4h..4h+3 (dwords 2h,2h+1)
    const int hw = lane >> 5;        // 0: owns type tp, 1: owns type tp+1
    // swizzled 8B destination: granule (h>>1)^(row&7), byte (h&1)*8 within it
    char* rowb = aggb + (size_t)(wid >> 7) * 32768 + (size_t)(wid & 127) * 256
               + (size_t)(((h >> 1) ^ (wid & 7)) << 4) + (h & 1) * 8;
    const size_t tstride = (size_t)nc * 256;
    unsigned msk = 0;

    #pragma unroll
    for (int tp = 0; tp < 7; tp += 2) {
        const int cA = ct[tp];
        const int cB = (tp + 1 < 7) ? ct[tp + 1] : 0;
        const int sA = st[tp];
        const int sB = (tp + 1 < 7) ? st[tp + 1] : 0;
        const int cM = hw ? cB : cA;         // my half's exact count (per-lane)
        const int sM = hw ? sB : sA;
        const int cMax = cA > cB ? cA : cB;  // WAVE-UNIFORM loop bound

        float a0 = 0.f, a1 = 0.f, a2 = 0.f, a3 = 0.f;
        for (int e = 0; e < cMax; e += 2) {  // uniform bound: all lanes loop
            int i0 = (sM + e) & 63;
            int i1 = (sM + e + 1) & 63;
            int r0 = __shfl(val2, i0);       // ALL 64 lanes active (required)
            int r1 = __shfl(val2, i1);
            int s0_ = (e < cM)     ? r0 : NN;     // pad -> zero row
            int s1_ = (e + 1 < cM) ? r1 : NN;
            uint2 v0 = *(const uint2*)(xb + (size_t)s0_ * 256 + h * 8);
            uint2 v1 = *(const uint2*)(xb + (size_t)s1_ * 256 + h * 8);
            a0 += __uint_as_float(v0.x << 16) + __uint_as_float(v1.x << 16);
            a1 += __uint_as_float(v0.x & 0xFFFF0000u) + __uint_as_float(v1.x & 0xFFFF0000u);
            a2 += __uint_as_float(v0.y << 16) + __uint_as_float(v1.y << 16);
            a3 += __uint_as_float(v0.y & 0xFFFF0000u) + __uint_as_float(v1.y & 0xFFFF0000u);
        }
        float sc = 1.0f / fmaxf((float)cM, 1.0f);   // mean folded pre-GEMM
        if (tp + hw < 7) {                   // half1 has no type when tp==6
            uint2 d;
            d.x = pack_bf16x2(a0 * sc, a1 * sc);
            d.y = pack_bf16x2(a2 * sc, a3 * sc);
            *(uint2*)(rowb + (size_t)(tp + hw) * tstride) = d;
        }
        msk |= (cA > 0) ? (1u << tp) : 0u;
        if (tp + 1 < 7) msk |= (cB > 0) ? (1u << (tp + 1)) : 0u;
    }
    if (live && lane == 0) bmask[n] = (unsigned char)msk;
}

// ------------------------------------------------------------------ gemm ----
// R10 structure: 512 threads = 8 waves; wave w=(wy,wx): rows wy*32..+31,
// cols wx*64..+63. K-loop over 7 types (K=896, BK=128). Bias via bmask.
__global__ __launch_bounds__(512) void gemm_k(
    const char* __restrict__ aggb, const char* __restrict__ WTb,
    const unsigned char* __restrict__ bmask, const float* __restrict__ bias,
    float* __restrict__ out, int c0, int nc)
{
    __shared__ char sA[128 * 256];   // 32 KB
    __shared__ char sW[128 * 256];   // 32 KB
    int tid = threadIdx.x;
    int w = tid >> 6, lane = tid & 63;
    int wy = w >> 1, wx = w & 1;
    int n0 = c0 + blockIdx.x * 128;
    const size_t tstride = (size_t)nc * 256;

    f32x4 acc[2][4];
    #pragma unroll
    for (int i = 0; i < 2; ++i)
        #pragma unroll
        for (int j = 0; j < 4; ++j) acc[i][j] = (f32x4)0.0f;

    for (int t = 0; t < NT; ++t) {
        __syncthreads();   // prev MFMA readers done before restage
        const char* asrc = aggb + (size_t)t * tstride + (size_t)blockIdx.x * 32768;
        const char* wsrc = WTb + (size_t)t * 32768;
        #pragma unroll
        for (int i = 0; i < 4; ++i) {
            int ch = w * 4 + i;     // 32 chunks x 1KB each
            __builtin_amdgcn_global_load_lds(
                (const __attribute__((address_space(1))) void*)(asrc + ch * 1024 + lane * 16),
                (__attribute__((address_space(3))) void*)(sA + ch * 1024), 16, 0, 0);
            __builtin_amdgcn_global_load_lds(
                (const __attribute__((address_space(1))) void*)(wsrc + ch * 1024 + lane * 16),
                (__attribute__((address_space(3))) void*)(sW + ch * 1024), 16, 0, 0);
        }
        __syncthreads();   // compiler drains vmcnt before barrier

        #pragma unroll
        for (int c = 0; c < 4; ++c) {
            int gsel = ((c * 4 + (lane >> 4)) ^ (lane & 7)) << 4;
            bf16x8 A0 = *(const bf16x8*)(sA + (wy * 32 + (lane & 15)) * 256 + gsel);
            bf16x8 A1 = *(const bf16x8*)(sA + (wy * 32 + 16 + (lane & 15)) * 256 + gsel);
            #pragma unroll
            for (int nj = 0; nj < 4; ++nj) {
                bf16x8 B = *(const bf16x8*)(sW + (wx * 64 + nj * 16 + (lane & 15)) * 256 + gsel);
                acc[0][nj] = __builtin_amdgcn_mfma_f32_16x16x32_bf16(A0, B, acc[0][nj], 0, 0, 0);
                acc[1][nj] = __builtin_amdgcn_mfma_f32_16x16x32_bf16(A1, B, acc[1][nj], 0, 0, 0);
            }
        }
    }

    // epilogue: mean over types + per-type bias where the node has edges
    const float inv7 = 1.0f / (float)NT;
    #pragma unroll
    for (int mi = 0; mi < 2; ++mi) {
        #pragma unroll
        for (int v = 0; v < 4; ++v) {
            int n = n0 + wy * 32 + mi * 16 + (lane >> 4) * 4 + v;
            if (n >= NN) continue;
            unsigned mk = bmask[n];
            float add[4] = {0.f, 0.f, 0.f, 0.f};
            #pragma unroll
            for (int t = 0; t < NT; ++t) {
                if ((mk >> t) & 1u) {
                    #pragma unroll
                    for (int nj = 0; nj < 4; ++nj)
                        add[nj] += bias[(size_t)t * DD + wx * 64 + nj * 16 + (lane & 15)];
                }
            }
            #pragma unroll
            for (int nj = 0; nj < 4; ++nj)
                out[(size_t)n * DD + wx * 64 + nj * 16 + (lane & 15)]
                    = inv7 * (acc[mi][nj][v] + add[nj]);
        }
    }
}

// ---------------------------------------------------------------- launch ----
extern "C" void kernel_launch(void* const* d_in, const int* in_sizes, int n_in,
                              void* d_out, int out_size, void* d_ws, size_t ws_size,
                              hipStream_t stream) {
    const float* x  = (const float*)d_in[0];
    const int*   ei = (const int*)d_in[1];
    const float* W  = (const float*)d_in[2];
    const float* b  = (const float*)d_in[3];
    float* out = (float*)d_out;
    char* ws = (char*)d_ws;

    // fixed tables: ~52 MB; aggb 179.4 MB -> total ~231 MB (ws proven)
    size_t off = 0;
    char* xb     = ws + off; off += (size_t)(NN + 1) * 256;            // 25.6 MB
    char* WTb    = ws + off; off += (size_t)NT * 128 * 256;            // 224 KB
    int*  eslots = (int*)(ws + off); off += (size_t)NN * 64 * 4;       // 25.6 MB
    int*  cntT   = (int*)(ws + off); off += (size_t)NN * 4;            // 400 KB
    unsigned char* bmask = (unsigned char*)(ws + off); off += (size_t)NN; // 100 KB
    off = (off + 255) & ~(size_t)255;
    char* aggb   = ws + off;                                           // remainder

    size_t avail = (ws_size > off) ? (ws_size - off) : 0;
    int Nc = (int)(avail / ((size_t)NT * 256));
    Nc &= ~127;
    if (Nc < 128) Nc = 128;
    if (Nc > NROWS) Nc = NROWS;

    convx_k<<<(NN * DD / 8 + 255) / 256, 256, 0, stream>>>(x, (uint4*)xb);
    hipMemsetAsync(xb + (size_t)NN * 256, 0, 256, stream);   // zero pad row
    wconv_k<<<(NT * 128 + 3) / 4, 256, 0, stream>>>(W, WTb);
    hipMemsetAsync(cntT, 0, (size_t)NN * 4, stream);
    fill_k<<<dim3(NSLAB * NPART, NT), 256, 0, stream>>>(ei, cntT, eslots);

    for (int c0 = 0; c0 < NN; c0 += Nc) {
        int nc = (NROWS - c0 < Nc) ? (NROWS - c0) : Nc;   // multiple of 128
        agg_k<<<nc / 4, 256, 0, stream>>>(xb, cntT, eslots, aggb, bmask, c0, nc);
        gemm_k<<<nc / 128, 512, 0, stream>>>(aggb, WTb, bmask, b, out, c0, nc);
    }
}